// Round 1
// baseline (2867.145 us; speedup 1.0000x reference)
//
#include <hip/hip_runtime.h>

#define NN 100000
#define H 64

// ---------------- kernels ----------------

__global__ void k_deg(const int* __restrict__ col, const float* __restrict__ ew,
                      float* __restrict__ deg, int E) {
    int e = blockIdx.x * blockDim.x + threadIdx.x;
    if (e < E) atomicAdd(&deg[col[e]], ew[e]);
}

// fused: dinv = rsqrt(deg+1); xw1 = x @ W1; xs1 = xw1*dinv; acc1 = dinv*xs1 (self loop)
__global__ void k_l1_init(const float* __restrict__ x, const float* __restrict__ W1,
                          const float* __restrict__ deg, float* __restrict__ dinv,
                          float* __restrict__ xs1, float* __restrict__ acc1, int n) {
    __shared__ float w[4 * H];
    int t = threadIdx.x;
    if (t < 4 * H) w[t] = W1[t];
    __syncthreads();
    int g = blockIdx.x * blockDim.x + t;
    int i = g >> 4;          // node
    int q = (g & 15) * 4;    // output column base (4 cols per thread)
    if (i >= n) return;
    float di = rsqrtf(deg[i] + 1.0f);   // +1 = self-loop weight
    if ((g & 15) == 0) dinv[i] = di;
    float x0 = x[i * 4 + 0], x1 = x[i * 4 + 1], x2 = x[i * 4 + 2], x3 = x[i * 4 + 3];
    float4 xsv, accv;
    float* pxs = xs1 + (size_t)i * H + q;
    float* pac = acc1 + (size_t)i * H + q;
#pragma unroll
    for (int j = 0; j < 4; ++j) {
        int c = q + j;
        float v = x0 * w[c] + x1 * w[H + c] + x2 * w[2 * H + c] + x3 * w[3 * H + c];
        float xsf = v * di;
        (&xsv.x)[j] = xsf;
        (&accv.x)[j] = di * xsf;
    }
    *(float4*)pxs = xsv;
    *(float4*)pac = accv;
}

// edge aggregation: acc[col] += xs[row] * (ew * dinv[col]);  16 lanes per edge
__global__ void k_agg(const int* __restrict__ row, const int* __restrict__ col,
                      const float* __restrict__ ew, const float* __restrict__ dinv,
                      const float* __restrict__ xs, float* __restrict__ acc, int E) {
    int g = blockIdx.x * blockDim.x + threadIdx.x;
    int e = g >> 4;
    if (e >= E) return;
    int q = (g & 15) * 4;
    int r = row[e], c = col[e];
    float s = ew[e] * dinv[c];
    const float4 v = *(const float4*)(xs + (size_t)r * H + q);
    float* p = acc + (size_t)c * H + q;
    atomicAdd(p + 0, v.x * s);
    atomicAdd(p + 1, v.y * s);
    atomicAdd(p + 2, v.z * s);
    atomicAdd(p + 3, v.w * s);
}

// fused layer2 front: h = relu(acc1+b1); xw2 = h@W2; xs2 = xw2*dinv; acc2 = dinv*xs2
// one wave (64 lanes) per node, W2 staged in LDS
__global__ void k_l2(const float* __restrict__ acc1, const float* __restrict__ b1,
                     const float* __restrict__ W2, const float* __restrict__ dinv,
                     float* __restrict__ xs2, float* __restrict__ acc2, int n) {
    __shared__ float w[H * H];
    __shared__ float hs[4][H];
    for (int t = threadIdx.x; t < H * H; t += 256) w[t] = W2[t];
    int wave = threadIdx.x >> 6, lane = threadIdx.x & 63;
    int i = blockIdx.x * 4 + wave;
    bool valid = i < n;
    float h = 0.0f;
    if (valid) h = fmaxf(acc1[(size_t)i * H + lane] + b1[lane], 0.0f);
    hs[wave][lane] = h;
    __syncthreads();   // also covers the W2 staging
    float a = 0.0f;
#pragma unroll
    for (int k = 0; k < H; ++k) a = fmaf(hs[wave][k], w[k * H + lane], a);
    if (valid) {
        float di = dinv[i];
        float xsf = a * di;
        xs2[(size_t)i * H + lane] = xsf;
        acc2[(size_t)i * H + lane] = di * xsf;
    }
}

// final: out = relu(out + b2), in place, float4
__global__ void k_bias_relu(float* __restrict__ out, const float* __restrict__ b2, int n4) {
    int g = blockIdx.x * blockDim.x + threadIdx.x;
    if (g >= n4) return;
    int j = (g & (H / 4 - 1)) * 4;
    float4 v = ((float4*)out)[g];
    v.x = fmaxf(v.x + b2[j + 0], 0.0f);
    v.y = fmaxf(v.y + b2[j + 1], 0.0f);
    v.z = fmaxf(v.z + b2[j + 2], 0.0f);
    v.w = fmaxf(v.w + b2[j + 3], 0.0f);
    ((float4*)out)[g] = v;
}

// ---------------- launcher ----------------

extern "C" void kernel_launch(void* const* d_in, const int* in_sizes, int n_in,
                              void* d_out, int out_size, void* d_ws, size_t ws_size,
                              hipStream_t stream) {
    const float* x  = (const float*)d_in[0];
    const int*   ei = (const int*)d_in[1];     // [2, E] row-major: row then col
    const float* ew = (const float*)d_in[2];
    const float* W1 = (const float*)d_in[3];
    const float* b1 = (const float*)d_in[4];
    const float* W2 = (const float*)d_in[5];
    const float* b2 = (const float*)d_in[6];
    float* out = (float*)d_out;

    const int n = in_sizes[0] / 4;     // 100000
    const int E = in_sizes[2];         // 1600000
    const int* row = ei;
    const int* col = ei + E;

    // workspace layout (fp32): deg[n] | dinv[n] | xs[n*64] | acc1[n*64]
    float* deg  = (float*)d_ws;
    float* dinv = deg + n;
    float* xs   = dinv + n;            // xs1, later reused as xs2
    float* acc1 = xs + (size_t)n * H;

    hipMemsetAsync(deg, 0, (size_t)n * sizeof(float), stream);

    k_deg<<<(E + 255) / 256, 256, 0, stream>>>(col, ew, deg, E);

    k_l1_init<<<(n * 16 + 255) / 256, 256, 0, stream>>>(x, W1, deg, dinv, xs, acc1, n);

    k_agg<<<(int)(((size_t)E * 16 + 255) / 256), 256, 0, stream>>>(row, col, ew, dinv, xs, acc1, E);

    k_l2<<<(n + 3) / 4, 256, 0, stream>>>(acc1, b1, W2, dinv, xs, out, n);

    k_agg<<<(int)(((size_t)E * 16 + 255) / 256), 256, 0, stream>>>(row, col, ew, dinv, xs, out, E);

    k_bias_relu<<<(n * (H / 4) + 255) / 256, 256, 0, stream>>>(out, b2, n * (H / 4));
}

// Round 2
// 493.880 us; speedup vs baseline: 5.8054x; 5.8054x over previous
//
#include <hip/hip_runtime.h>

#define H 64

// ---------------- CSR build ----------------

__global__ void k_count(const int* __restrict__ col, int* __restrict__ cnt, int E) {
    int e = blockIdx.x * blockDim.x + threadIdx.x;
    if (e < E) atomicAdd(&cnt[col[e]], 1);
}

// assign each node a contiguous segment (order nondeterministic, values deterministic per node)
__global__ void k_base(const int* __restrict__ cnt, int* __restrict__ total,
                       int* __restrict__ start, int* __restrict__ cursor, int n) {
    int i = blockIdx.x * blockDim.x + threadIdx.x;
    if (i >= n) return;
    int v = cnt[i];
    int b = atomicAdd(total, v);
    start[i] = b;
    cursor[i] = b;
}

__global__ void k_scatter(const int* __restrict__ row, const int* __restrict__ col,
                          const float* __restrict__ ew, int* __restrict__ cursor,
                          int2* __restrict__ sorted, int E) {
    int e = blockIdx.x * blockDim.x + threadIdx.x;
    if (e >= E) return;
    int c = col[e];
    int pos = atomicAdd(&cursor[c], 1);
    sorted[pos] = make_int2(row[e], __float_as_int(ew[e]));
}

// weighted in-degree (incl. self loop weight 1) from sorted segments -> dinv
__global__ void k_degdinv(const int2* __restrict__ sorted, const int* __restrict__ start,
                          const int* __restrict__ cnt, float* __restrict__ dinv, int n) {
    int i = blockIdx.x * blockDim.x + threadIdx.x;
    if (i >= n) return;
    int s = start[i], e = s + cnt[i];
    float d = 1.0f;
    for (int j = s; j < e; ++j) d += __int_as_float(sorted[j].y);
    dinv[i] = rsqrtf(d);
}

// ---------------- layer fronts ----------------

// xs1 = (x @ W1) * dinv[i]; 16 threads per node, 4 cols each
__global__ void k_l1(const float* __restrict__ x, const float* __restrict__ W1,
                     const float* __restrict__ dinv, float* __restrict__ xs, int n) {
    __shared__ float w[4 * H];
    int t = threadIdx.x;
    if (t < 4 * H) w[t] = W1[t];
    __syncthreads();
    int g = blockIdx.x * blockDim.x + t;
    int i = g >> 4;
    int q = (g & 15) * 4;
    if (i >= n) return;
    float di = dinv[i];
    float x0 = x[i * 4 + 0], x1 = x[i * 4 + 1], x2 = x[i * 4 + 2], x3 = x[i * 4 + 3];
    float4 xsv;
#pragma unroll
    for (int j = 0; j < 4; ++j) {
        int c = q + j;
        float v = x0 * w[c] + x1 * w[H + c] + x2 * w[2 * H + c] + x3 * w[3 * H + c];
        (&xsv.x)[j] = v * di;
    }
    *(float4*)(xs + (size_t)i * H + q) = xsv;
}

// h = relu(acc1 + b1); xs2 = (h @ W2) * dinv; one wave per node, W2 in LDS
__global__ void k_l2(const float* __restrict__ acc1, const float* __restrict__ b1,
                     const float* __restrict__ W2, const float* __restrict__ dinv,
                     float* __restrict__ xs2, int n) {
    __shared__ float w[H * H];
    __shared__ float hs[4][H];
    for (int t = threadIdx.x; t < H * H; t += 256) w[t] = W2[t];
    int wave = threadIdx.x >> 6, lane = threadIdx.x & 63;
    int i = blockIdx.x * 4 + wave;
    bool valid = i < n;
    float h = 0.0f;
    if (valid) h = fmaxf(acc1[(size_t)i * H + lane] + b1[lane], 0.0f);
    hs[wave][lane] = h;
    __syncthreads();
    float a = 0.0f;
#pragma unroll
    for (int k = 0; k < H; ++k) a = fmaf(hs[wave][k], w[k * H + lane], a);
    if (valid) xs2[(size_t)i * H + lane] = a * dinv[i];
}

// ---------------- CSR aggregation: one wave per node ----------------
// out[i] = dinv[i]*(xs[i] + sum_e xs[row_e]*ew_e)   (+ bias, relu when FINAL)

template <bool FINAL>
__global__ void k_agg(const int2* __restrict__ sorted, const int* __restrict__ start,
                      const int* __restrict__ cnt, const float* __restrict__ dinv,
                      const float* __restrict__ xs, const float* __restrict__ bias,
                      float* __restrict__ out, int n) {
    int wid = (blockIdx.x * blockDim.x + threadIdx.x) >> 6;
    int lane = threadIdx.x & 63;
    if (wid >= n) return;
    int s = start[wid], e = s + cnt[wid];
    float a = xs[(size_t)wid * H + lane];   // self loop (weight 1)
    int j = s;
    for (; j + 1 < e; j += 2) {
        int2 p0 = sorted[j];
        int2 p1 = sorted[j + 1];
        float v0 = xs[(size_t)p0.x * H + lane];
        float v1 = xs[(size_t)p1.x * H + lane];
        a = fmaf(v0, __int_as_float(p0.y), a);
        a = fmaf(v1, __int_as_float(p1.y), a);
    }
    if (j < e) {
        int2 p = sorted[j];
        a = fmaf(xs[(size_t)p.x * H + lane], __int_as_float(p.y), a);
    }
    float r = a * dinv[wid];
    if (FINAL) r = fmaxf(r + bias[lane], 0.0f);
    out[(size_t)wid * H + lane] = r;
}

// ---------------- launcher ----------------

extern "C" void kernel_launch(void* const* d_in, const int* in_sizes, int n_in,
                              void* d_out, int out_size, void* d_ws, size_t ws_size,
                              hipStream_t stream) {
    const float* x  = (const float*)d_in[0];
    const int*   ei = (const int*)d_in[1];     // [2, E]: row then col
    const float* ew = (const float*)d_in[2];
    const float* W1 = (const float*)d_in[3];
    const float* b1 = (const float*)d_in[4];
    const float* W2 = (const float*)d_in[5];
    const float* b2 = (const float*)d_in[6];
    float* out = (float*)d_out;

    const int n = in_sizes[0] / 4;     // 100000
    const int E = in_sizes[2];         // 1600000
    const int* row = ei;
    const int* col = ei + E;

    // ws layout: cnt[n] | total[1] | start[n] | cursor[n] | dinv[n] | xs[n*64] | acc1[n*64] | sorted[E] (int2)
    char* p = (char*)d_ws;
    int*   cnt    = (int*)p;                 p += (size_t)n * 4;
    int*   total  = (int*)p;                 p += 4;
    int*   start  = (int*)p;                 p += (size_t)n * 4;
    int*   cursor = (int*)p;                 p += (size_t)n * 4;
    float* dinv   = (float*)p;               p += (size_t)n * 4;
    float* xs     = (float*)p;               p += (size_t)n * H * 4;
    float* acc1   = (float*)p;               p += (size_t)n * H * 4;
    int2*  sorted = (int2*)p;

    // zero cnt + total in one shot (adjacent)
    hipMemsetAsync(cnt, 0, ((size_t)n + 1) * 4, stream);

    k_count<<<(E + 255) / 256, 256, 0, stream>>>(col, cnt, E);
    k_base<<<(n + 255) / 256, 256, 0, stream>>>(cnt, total, start, cursor, n);
    k_scatter<<<(E + 255) / 256, 256, 0, stream>>>(row, col, ew, cursor, sorted, E);
    k_degdinv<<<(n + 255) / 256, 256, 0, stream>>>(sorted, start, cnt, dinv, n);

    k_l1<<<(n * 16 + 255) / 256, 256, 0, stream>>>(x, W1, dinv, xs, n);

    int aggBlocks = (int)(((size_t)n * 64 + 255) / 256);
    k_agg<false><<<aggBlocks, 256, 0, stream>>>(sorted, start, cnt, dinv, xs, nullptr, acc1, n);

    k_l2<<<(n + 3) / 4, 256, 0, stream>>>(acc1, b1, W2, dinv, xs, n);

    k_agg<true><<<aggBlocks, 256, 0, stream>>>(sorted, start, cnt, dinv, xs, b2, out, n);
}

// Round 3
// 421.521 us; speedup vs baseline: 6.8019x; 1.1717x over previous
//
#include <hip/hip_runtime.h>

#define H 64
#define WSCALE (1.0f / 32768.0f)

// ---- helpers ----
__device__ __forceinline__ float bf2f(unsigned short u) {
    return __uint_as_float(((unsigned)u) << 16);
}
__device__ __forceinline__ unsigned short f2bf(float f) {  // RNE
    unsigned u = __float_as_uint(f);
    unsigned r = ((u >> 16) & 1u) + 0x7FFFu;
    return (unsigned short)((u + r) >> 16);
}

// ---------------- CSR build ----------------

__global__ void k_count(const int* __restrict__ col, int* __restrict__ cnt, int E) {
    int e = blockIdx.x * blockDim.x + threadIdx.x;
    if (e < E) atomicAdd(&cnt[col[e]], 1);
}

__global__ void k_base(const int* __restrict__ cnt, int* __restrict__ total,
                       int* __restrict__ start, int* __restrict__ cursor, int n) {
    int i = blockIdx.x * blockDim.x + threadIdx.x;
    if (i >= n) return;
    int v = cnt[i];
    int b = atomicAdd(total, v);
    start[i] = b;
    cursor[i] = b;
}

// payload: bits[16:0] = row, bits[31:17] = round(w * 32768) (w in [0,1))
__global__ void k_scatter(const int* __restrict__ row, const int* __restrict__ col,
                          const float* __restrict__ ew, int* __restrict__ cursor,
                          unsigned* __restrict__ sorted, int E) {
    int e = blockIdx.x * blockDim.x + threadIdx.x;
    if (e >= E) return;
    int c = col[e];
    int q = (int)(ew[e] * 32768.0f + 0.5f);
    if (q > 32767) q = 32767;
    unsigned pk = ((unsigned)q << 17) | (unsigned)row[e];
    int pos = atomicAdd(&cursor[c], 1);
    sorted[pos] = pk;
}

__global__ void k_degdinv(const unsigned* __restrict__ sorted, const int* __restrict__ start,
                          const int* __restrict__ cnt, float* __restrict__ dinv, int n) {
    int i = blockIdx.x * blockDim.x + threadIdx.x;
    if (i >= n) return;
    int s = start[i], e = s + cnt[i];
    float d = 1.0f;
    for (int j = s; j < e; ++j) d += (float)(sorted[j] >> 17) * WSCALE;
    dinv[i] = rsqrtf(d);
}

// ---------------- layer fronts ----------------

// xs1 = (x @ W1) * dinv[i], stored bf16; 16 threads per node, 4 cols each
__global__ void k_l1(const float* __restrict__ x, const float* __restrict__ W1,
                     const float* __restrict__ dinv, unsigned short* __restrict__ xsb, int n) {
    __shared__ float w[4 * H];
    int t = threadIdx.x;
    if (t < 4 * H) w[t] = W1[t];
    __syncthreads();
    int g = blockIdx.x * blockDim.x + t;
    int i = g >> 4;
    int q = (g & 15) * 4;
    if (i >= n) return;
    float di = dinv[i];
    float x0 = x[i * 4 + 0], x1 = x[i * 4 + 1], x2 = x[i * 4 + 2], x3 = x[i * 4 + 3];
    ushort4 outv;
#pragma unroll
    for (int j = 0; j < 4; ++j) {
        int c = q + j;
        float v = x0 * w[c] + x1 * w[H + c] + x2 * w[2 * H + c] + x3 * w[3 * H + c];
        (&outv.x)[j] = f2bf(v * di);
    }
    *(ushort4*)(xsb + (size_t)i * H + q) = outv;
}

// h = relu(acc1 + b1); xs2 = (h @ W2) * dinv, stored bf16; one wave per node
__global__ void k_l2(const float* __restrict__ acc1, const float* __restrict__ b1,
                     const float* __restrict__ W2, const float* __restrict__ dinv,
                     unsigned short* __restrict__ xsb, int n) {
    __shared__ float w[H * H];
    __shared__ float hs[4][H];
    for (int t = threadIdx.x; t < H * H; t += 256) w[t] = W2[t];
    int wave = threadIdx.x >> 6, lane = threadIdx.x & 63;
    int i = blockIdx.x * 4 + wave;
    bool valid = i < n;
    float h = 0.0f;
    if (valid) h = fmaxf(acc1[(size_t)i * H + lane] + b1[lane], 0.0f);
    hs[wave][lane] = h;
    __syncthreads();
    float a = 0.0f;
#pragma unroll
    for (int k = 0; k < H; ++k) a = fmaf(hs[wave][k], w[k * H + lane], a);
    if (valid) xsb[(size_t)i * H + lane] = f2bf(a * dinv[i]);
}

// ---------------- CSR aggregation: one wave per node ----------------
// out[i] = dinv[i]*(xs[i] + sum_e xs[row_e]*ew_e)   (+ bias, relu when FINAL)

template <bool FINAL>
__global__ void k_agg(const unsigned* __restrict__ sorted, const int* __restrict__ start,
                      const int* __restrict__ cnt, const float* __restrict__ dinv,
                      const unsigned short* __restrict__ xsb, const float* __restrict__ bias,
                      float* __restrict__ out, int n) {
    int wid = (blockIdx.x * blockDim.x + threadIdx.x) >> 6;
    int lane = threadIdx.x & 63;
    if (wid >= n) return;
    int s = start[wid], e = s + cnt[wid];
    float a = bf2f(xsb[(size_t)wid * H + lane]);   // self loop (weight 1)
    int j = s;
    for (; j + 3 < e; j += 4) {
        unsigned p0 = sorted[j], p1 = sorted[j + 1], p2 = sorted[j + 2], p3 = sorted[j + 3];
        float v0 = bf2f(xsb[(size_t)(p0 & 0x1FFFFu) * H + lane]);
        float v1 = bf2f(xsb[(size_t)(p1 & 0x1FFFFu) * H + lane]);
        float v2 = bf2f(xsb[(size_t)(p2 & 0x1FFFFu) * H + lane]);
        float v3 = bf2f(xsb[(size_t)(p3 & 0x1FFFFu) * H + lane]);
        a = fmaf(v0, (float)(p0 >> 17) * WSCALE, a);
        a = fmaf(v1, (float)(p1 >> 17) * WSCALE, a);
        a = fmaf(v2, (float)(p2 >> 17) * WSCALE, a);
        a = fmaf(v3, (float)(p3 >> 17) * WSCALE, a);
    }
    for (; j < e; ++j) {
        unsigned p = sorted[j];
        a = fmaf(bf2f(xsb[(size_t)(p & 0x1FFFFu) * H + lane]), (float)(p >> 17) * WSCALE, a);
    }
    float r = a * dinv[wid];
    if (FINAL) r = fmaxf(r + bias[lane], 0.0f);
    out[(size_t)wid * H + lane] = r;
}

// ---------------- launcher ----------------

extern "C" void kernel_launch(void* const* d_in, const int* in_sizes, int n_in,
                              void* d_out, int out_size, void* d_ws, size_t ws_size,
                              hipStream_t stream) {
    const float* x  = (const float*)d_in[0];
    const int*   ei = (const int*)d_in[1];     // [2, E]: row then col
    const float* ew = (const float*)d_in[2];
    const float* W1 = (const float*)d_in[3];
    const float* b1 = (const float*)d_in[4];
    const float* W2 = (const float*)d_in[5];
    const float* b2 = (const float*)d_in[6];
    float* out = (float*)d_out;

    const int n = in_sizes[0] / 4;     // 100000
    const int E = in_sizes[2];         // 1600000
    const int* row = ei;
    const int* col = ei + E;

    // ws: cnt[n] | total[1] | start[n] | cursor[n] | dinv[n] | xsb[n*64] bf16 | acc1[n*64] f32 | sorted[E] u32
    char* p = (char*)d_ws;
    int*   cnt    = (int*)p;                 p += (size_t)n * 4;
    int*   total  = (int*)p;                 p += 4;
    int*   start  = (int*)p;                 p += (size_t)n * 4;
    int*   cursor = (int*)p;                 p += (size_t)n * 4;
    float* dinv   = (float*)p;               p += (size_t)n * 4;
    unsigned short* xsb = (unsigned short*)p; p += (size_t)n * H * 2;
    float* acc1   = (float*)p;               p += (size_t)n * H * 4;
    unsigned* sorted = (unsigned*)p;

    hipMemsetAsync(cnt, 0, ((size_t)n + 1) * 4, stream);

    k_count<<<(E + 255) / 256, 256, 0, stream>>>(col, cnt, E);
    k_base<<<(n + 255) / 256, 256, 0, stream>>>(cnt, total, start, cursor, n);
    k_scatter<<<(E + 255) / 256, 256, 0, stream>>>(row, col, ew, cursor, sorted, E);
    k_degdinv<<<(n + 255) / 256, 256, 0, stream>>>(sorted, start, cnt, dinv, n);

    k_l1<<<(n * 16 + 255) / 256, 256, 0, stream>>>(x, W1, dinv, xsb, n);

    int aggBlocks = (int)(((size_t)n * 64 + 255) / 256);
    k_agg<false><<<aggBlocks, 256, 0, stream>>>(sorted, start, cnt, dinv, xsb, nullptr, acc1, n);

    k_l2<<<(n + 3) / 4, 256, 0, stream>>>(acc1, b1, W2, dinv, xsb, n);

    k_agg<true><<<aggBlocks, 256, 0, stream>>>(sorted, start, cnt, dinv, xsb, b2, out, n);
}